// Round 14
// baseline (946.507 us; speedup 1.0000x reference)
//
#include <hip/hip_runtime.h>
#include <hip/hip_bf16.h>

// FP8Linear: out = Xq @ Wq^T + bias. Reference quantize (scale=1) == RNE
// conversion to OCP e4m3fn; x stored as e4m3(x); w stored as e4m3(w*2^6)
// with MFMA B-scale 2^-6 (e8m0 0x79) so all |w|>=2^-12 quantize EXACTLY.
// GEMM R14: combine R11's low-conflict layout with R13's concurrency.
// 128x128 tile, BK=128 (128B rows: fragment-read start banks are 8-way
// spread -> conflict rate 5-7e7, vs 2e8 at 64B rows/R13), 4 waves (2x2,
// 64x64 out, acc[2][2]), dbuf 64KB static LDS -> 2 INDEPENDENT blocks/CU
// (no cross-block lockstep; port and MFMA pipes overlap across blocks),
// DMA prefetch one full tile ahead, ONE __syncthreads per tile.
// mfma_scale_f32_32x32x64_f8f6f4; pre-swizzled DMA source; XCD swizzle.

typedef int i32x4 __attribute__((ext_vector_type(4)));
typedef int i32x8 __attribute__((ext_vector_type(8)));
typedef float f32x16 __attribute__((ext_vector_type(16)));

#define BM 128
#define BN 128
#define BK 128

// clip to +-448, scale (1 or 64), RNE-encode 8 f32 -> 8 e4m3 bytes.
__global__ __launch_bounds__(256) void quant8(
    const float4* __restrict__ in, int2* __restrict__ out, int n8, float scale) {
    int i = blockIdx.x * blockDim.x + threadIdx.x;
    if (i >= n8) return;
    float4 a = in[i * 2];
    float4 b = in[i * 2 + 1];
    float c0 = fminf(fmaxf(a.x, -448.f), 448.f) * scale;
    float c1 = fminf(fmaxf(a.y, -448.f), 448.f) * scale;
    float c2 = fminf(fmaxf(a.z, -448.f), 448.f) * scale;
    float c3 = fminf(fmaxf(a.w, -448.f), 448.f) * scale;
    float c4 = fminf(fmaxf(b.x, -448.f), 448.f) * scale;
    float c5 = fminf(fmaxf(b.y, -448.f), 448.f) * scale;
    float c6 = fminf(fmaxf(b.z, -448.f), 448.f) * scale;
    float c7 = fminf(fmaxf(b.w, -448.f), 448.f) * scale;
    int lo = __builtin_amdgcn_cvt_pk_fp8_f32(c0, c1, 0, false);
    lo = __builtin_amdgcn_cvt_pk_fp8_f32(c2, c3, lo, true);
    int hi = __builtin_amdgcn_cvt_pk_fp8_f32(c4, c5, 0, false);
    hi = __builtin_amdgcn_cvt_pk_fp8_f32(c6, c7, hi, true);
    out[i] = make_int2(lo, hi);
}

__device__ __forceinline__ void gload_lds16(const void* g, void* l) {
    __builtin_amdgcn_global_load_lds(
        (const __attribute__((address_space(1))) void*)g,
        (__attribute__((address_space(3))) void*)l,
        16, 0, 0);
}

// 128B-row tiles. LDS[r][c] holds G[r][c ^ sw(r)], sw(r) = (r&7)<<4.
// Read one lane's 32-byte k-block (logical cols [c0, c0+32)) of `row`.
__device__ __forceinline__ i32x8 frag32(const unsigned char* base, int row, int c0) {
    const int sw = (row & 7) << 4;
    const unsigned char* p = base + row * 128;
    i32x4 lo = *(const i32x4*)(p + (c0 ^ sw));
    i32x4 hi = *(const i32x4*)(p + ((c0 + 16) ^ sw));
    i32x8 r;
    r[0] = lo[0]; r[1] = lo[1]; r[2] = lo[2]; r[3] = lo[3];
    r[4] = hi[0]; r[5] = hi[1]; r[6] = hi[2]; r[7] = hi[3];
    return r;
}

// A: Xq8 [M][K] e4m3, B: Wq8 [N][K] e4m3 (pre-scaled by 2^6), C: [M][N] f32
__global__ __launch_bounds__(256, 2) void gemm_fp8(
    const unsigned char* __restrict__ A, const unsigned char* __restrict__ B,
    const float* __restrict__ bias, float* __restrict__ C,
    int M, int N, int K) {
    // buf0: A [0,16K) B [16K,32K); buf1: A [32K,48K) B [48K,64K)
    __shared__ unsigned char lds[65536];

    const int tid = threadIdx.x;
    const int lane = tid & 63;
    const int wave = tid >> 6;
    const int wr = wave >> 1;  // 2x2 wave grid, 64x64 output each
    const int wc = wave & 1;

    // XCD-aware bijective block swizzle (nwg % 8 == 0)
    const int nwg = gridDim.x;
    const int per = nwg >> 3;
    const int bid = blockIdx.x;
    const int wg = (bid & 7) * per + (bid >> 3);
    const int mtiles = M / BM;
    const int bm = wg % mtiles;
    const int bn = wg / mtiles;

    const int arow0 = bm * BM, bcol0 = bn * BN;
    const int NT = K / BK;  // 32

    const int rl = lane & 31;    // fragment row-within-32 (A row / B col)
    const int g2 = lane >> 5;    // k-half selector within 64-byte mfma k-range

    const unsigned char* const Ag = A + (size_t)arow0 * K;
    const unsigned char* const Bg = B + (size_t)bcol0 * K;

    // staging (per 16KB matrix = 128 rows x 128B, 4 chunks of 32 rows):
    // thread t: row = c*32 + (t>>3), logical col = (t&7)*16, dst linear,
    // src pre-swizzled (both-sides rule).
    const int srow = tid >> 3;                       // 0..31
    const int ssrc_col = ((tid & 7) * 16) ^ (((tid >> 3) & 7) << 4);
    const int sdst = tid * 16;

    auto stage = [&](unsigned char* Lp, int kt) {
#pragma unroll
        for (int c = 0; c < 4; ++c)
            gload_lds16(Ag + (size_t)(c * 32 + srow) * K + kt + ssrc_col,
                        Lp + c * 4096 + sdst);
#pragma unroll
        for (int c = 0; c < 4; ++c)
            gload_lds16(Bg + (size_t)(c * 32 + srow) * K + kt + ssrc_col,
                        Lp + 16384 + c * 4096 + sdst);
    };

    f32x16 acc[2][2] = {};

    // ---- prologue: tile 0 -> buf0
    stage(lds, 0);
    __syncthreads();  // implicit vmcnt(0): tile 0 landed

    for (int t = 0; t < NT; ++t) {
        const int cur = t & 1;
        const unsigned char* Ab = lds + cur * 32768;
        const unsigned char* Bb = Ab + 16384;
        unsigned char* Anx = lds + (cur ^ 1) * 32768;

        // issue next tile's DMAs first: a full tile of latency cover
        if (t + 1 < NT) stage(Anx, (t + 1) * BK);

#pragma unroll
        for (int ks = 0; ks < 2; ++ks) {
            const int c0 = ks * 64 + g2 * 32;
            i32x8 af0 = frag32(Ab, wr * 64 + rl, c0);
            i32x8 af1 = frag32(Ab, wr * 64 + 32 + rl, c0);
            i32x8 bf0 = frag32(Bb, wc * 64 + rl, c0);
            i32x8 bf1 = frag32(Bb, wc * 64 + 32 + rl, c0);

            acc[0][0] = __builtin_amdgcn_mfma_scale_f32_32x32x64_f8f6f4(
                af0, bf0, acc[0][0], 0, 0, 0, 0x7F7F7F7F, 0, 0x79797979);
            acc[0][1] = __builtin_amdgcn_mfma_scale_f32_32x32x64_f8f6f4(
                af0, bf1, acc[0][1], 0, 0, 0, 0x7F7F7F7F, 0, 0x79797979);
            acc[1][0] = __builtin_amdgcn_mfma_scale_f32_32x32x64_f8f6f4(
                af1, bf0, acc[1][0], 0, 0, 0, 0x7F7F7F7F, 0, 0x79797979);
            acc[1][1] = __builtin_amdgcn_mfma_scale_f32_32x32x64_f8f6f4(
                af1, bf1, acc[1][1], 0, 0, 0, 0x7F7F7F7F, 0, 0x79797979);
        }

        // one sync/tile: DMAs issued ~full tile ago have landed; publishes
        // the next buffer and protects the one just consumed.
        __syncthreads();
    }

    // epilogue: 32x32 C/D: col = lane&31, row = (reg&3)+8*(reg>>2)+4*(lane>>5)
#pragma unroll
    for (int n = 0; n < 2; ++n) {
        int col = bcol0 + wc * 64 + n * 32 + rl;
        float bv = bias[col];
#pragma unroll
        for (int m = 0; m < 2; ++m) {
            int rowb = arow0 + wr * 64 + m * 32 + g2 * 4;
#pragma unroll
            for (int reg = 0; reg < 16; ++reg) {
                int row = rowb + (reg & 3) + 8 * (reg >> 2);
                C[(size_t)row * N + col] = acc[m][n][reg] + bv;
            }
        }
    }
}

extern "C" void kernel_launch(void* const* d_in, const int* in_sizes, int n_in,
                              void* d_out, int out_size, void* d_ws, size_t ws_size,
                              hipStream_t stream) {
    const float* x = (const float*)d_in[0];     // [M,K]
    const float* w = (const float*)d_in[1];     // [N,K]
    const float* bias = (const float*)d_in[2];  // [N]
    float* out = (float*)d_out;

    const int N = in_sizes[2];                 // 16384
    const int K = in_sizes[1] / N;             // 4096
    const int M = in_sizes[0] / K;             // 8192

    unsigned char* xq = (unsigned char*)d_ws;          // M*K = 33.5 MB
    unsigned char* wq = xq + (size_t)M * K;            // N*K = 67 MB

    int nx8 = M * K / 8;
    int nw8 = N * K / 8;
    quant8<<<(nx8 + 255) / 256, 256, 0, stream>>>(
        (const float4*)x, (int2*)xq, nx8, 1.0f);
    quant8<<<(nw8 + 255) / 256, 256, 0, stream>>>(
        (const float4*)w, (int2*)wq, nw8, 64.0f);

    int nwg = (M / BM) * (N / BN);  // 64*128 = 8192, %8==0
    gemm_fp8<<<nwg, 256, 0, stream>>>(
        xq, wq, bias, out, M, N, K);
}

// Round 15
// 794.036 us; speedup vs baseline: 1.1920x; 1.1920x over previous
//
#include <hip/hip_runtime.h>
#include <hip/hip_bf16.h>

// FP8Linear: out = Xq @ Wq^T + bias. Reference quantize (scale=1) == RNE
// conversion to OCP e4m3fn; x stored as e4m3(x); w stored as e4m3(w*2^6)
// with MFMA B-scale 2^-6 (e8m0 0x79) so all |w|>=2^-12 quantize EXACTLY.
// GEMM R15: best-measured settings + wave-parity ks-stagger.
// Session model (R9-R14): binding constraint is the within-block wave
// convoy (reads-phase then MFMA-phase serialize between barriers); bank
// conflicts and raw port totals have slack; occupancy hard-capped at
// ~16 waves/CU by acc[2][2]=64 AGPR + ~64 arch VGPR = 128 unified regs.
// Config: 128x256 tile (21 KB/MFLOP), BK=128 (low-conflict sw=(r&7)<<4),
// single 48KB LDS buffer, 8 waves (2Mx4N, 64x64 out), 2 blocks/CU (50%),
// stage->sync->compute->sync. NEW: odd waves process ks=1 before ks=0 so
// half the waves' MFMA clusters run under the other half's LDS-read time
// (f32 accumulation order change only; ~1ulp).
// mfma_scale_f32_32x32x64_f8f6f4; pre-swizzled DMA source; XCD swizzle.

typedef int i32x4 __attribute__((ext_vector_type(4)));
typedef int i32x8 __attribute__((ext_vector_type(8)));
typedef float f32x16 __attribute__((ext_vector_type(16)));

#define BM 128
#define BN 256
#define BK 128

// clip to +-448, scale (1 or 64), RNE-encode 8 f32 -> 8 e4m3 bytes.
__global__ __launch_bounds__(256) void quant8(
    const float4* __restrict__ in, int2* __restrict__ out, int n8, float scale) {
    int i = blockIdx.x * blockDim.x + threadIdx.x;
    if (i >= n8) return;
    float4 a = in[i * 2];
    float4 b = in[i * 2 + 1];
    float c0 = fminf(fmaxf(a.x, -448.f), 448.f) * scale;
    float c1 = fminf(fmaxf(a.y, -448.f), 448.f) * scale;
    float c2 = fminf(fmaxf(a.z, -448.f), 448.f) * scale;
    float c3 = fminf(fmaxf(a.w, -448.f), 448.f) * scale;
    float c4 = fminf(fmaxf(b.x, -448.f), 448.f) * scale;
    float c5 = fminf(fmaxf(b.y, -448.f), 448.f) * scale;
    float c6 = fminf(fmaxf(b.z, -448.f), 448.f) * scale;
    float c7 = fminf(fmaxf(b.w, -448.f), 448.f) * scale;
    int lo = __builtin_amdgcn_cvt_pk_fp8_f32(c0, c1, 0, false);
    lo = __builtin_amdgcn_cvt_pk_fp8_f32(c2, c3, lo, true);
    int hi = __builtin_amdgcn_cvt_pk_fp8_f32(c4, c5, 0, false);
    hi = __builtin_amdgcn_cvt_pk_fp8_f32(c6, c7, hi, true);
    out[i] = make_int2(lo, hi);
}

__device__ __forceinline__ void gload_lds16(const void* g, void* l) {
    __builtin_amdgcn_global_load_lds(
        (const __attribute__((address_space(1))) void*)g,
        (__attribute__((address_space(3))) void*)l,
        16, 0, 0);
}

// 128B-row tiles. LDS[r][c] holds G[r][c ^ sw(r)], sw(r) = (r&7)<<4.
// Read one lane's 32-byte k-block (logical cols [c0, c0+32)) of `row`.
__device__ __forceinline__ i32x8 frag32(const unsigned char* base, int row, int c0) {
    const int sw = (row & 7) << 4;
    const unsigned char* p = base + row * 128;
    i32x4 lo = *(const i32x4*)(p + (c0 ^ sw));
    i32x4 hi = *(const i32x4*)(p + ((c0 + 16) ^ sw));
    i32x8 r;
    r[0] = lo[0]; r[1] = lo[1]; r[2] = lo[2]; r[3] = lo[3];
    r[4] = hi[0]; r[5] = hi[1]; r[6] = hi[2]; r[7] = hi[3];
    return r;
}

// A: Xq8 [M][K] e4m3, B: Wq8 [N][K] e4m3 (pre-scaled by 2^6), C: [M][N] f32
__global__ __launch_bounds__(512, 2) void gemm_fp8(
    const unsigned char* __restrict__ A, const unsigned char* __restrict__ B,
    const float* __restrict__ bias, float* __restrict__ C,
    int M, int N, int K) {
    // single buffer: A [0,16K) + B [16K,48K)
    __shared__ unsigned char lds[49152];
    unsigned char* const lA = lds;
    unsigned char* const lB = lds + 16384;

    const int tid = threadIdx.x;
    const int lane = tid & 63;
    const int wave = tid >> 6;
    const int wr = wave >> 2;   // 0..1 -> 64 A-rows each
    const int wc = wave & 3;    // 0..3 -> 64 B-cols each
    const int ko = wave & 1;    // ks-stagger parity

    // XCD-aware bijective block swizzle (nwg % 8 == 0)
    const int nwg = gridDim.x;
    const int per = nwg >> 3;
    const int bid = blockIdx.x;
    const int wg = (bid & 7) * per + (bid >> 3);
    const int mtiles = M / BM;
    const int bm = wg % mtiles;
    const int bn = wg / mtiles;

    const int arow0 = bm * BM, bcol0 = bn * BN;
    const int NT = K / BK;  // 32

    const int rl = lane & 31;    // fragment row-within-32 (A row / B col)
    const int g2 = lane >> 5;    // k-half selector within 64-byte mfma k-range

    const unsigned char* const Ag = A + (size_t)arow0 * K;
    const unsigned char* const Bg = B + (size_t)bcol0 * K;

    // staging: 512 threads. A (16KB): 2 chunks of 64 rows; B (32KB): 4 chunks.
    // thread t: row-in-chunk = t>>3, logical col = (t&7)*16, dst linear,
    // src pre-swizzled (both-sides rule).
    const int srow = tid >> 3;                       // 0..63
    const int ssrc_col = ((tid & 7) * 16) ^ (((tid >> 3) & 7) << 4);
    const int sdst = tid * 16;

    auto stage = [&](int kt) {
#pragma unroll
        for (int c = 0; c < 2; ++c)
            gload_lds16(Ag + (size_t)(c * 64 + srow) * K + kt + ssrc_col,
                        lA + c * 8192 + sdst);
#pragma unroll
        for (int c = 0; c < 4; ++c)
            gload_lds16(Bg + (size_t)(c * 64 + srow) * K + kt + ssrc_col,
                        lB + c * 8192 + sdst);
    };

    f32x16 acc[2][2] = {};

    for (int t = 0; t < NT; ++t) {
        stage(t * BK);
        __syncthreads();  // implicit vmcnt(0): tile landed, visible to all

#pragma unroll
        for (int s = 0; s < 2; ++s) {
            const int ks = s ^ ko;  // odd waves run ks=1 first (stagger)
            const int c0 = ks * 64 + g2 * 32;
            i32x8 af0 = frag32(lA, wr * 64 + rl, c0);
            i32x8 af1 = frag32(lA, wr * 64 + 32 + rl, c0);
            i32x8 bf0 = frag32(lB, wc * 64 + rl, c0);
            i32x8 bf1 = frag32(lB, wc * 64 + 32 + rl, c0);

            acc[0][0] = __builtin_amdgcn_mfma_scale_f32_32x32x64_f8f6f4(
                af0, bf0, acc[0][0], 0, 0, 0, 0x7F7F7F7F, 0, 0x79797979);
            acc[0][1] = __builtin_amdgcn_mfma_scale_f32_32x32x64_f8f6f4(
                af0, bf1, acc[0][1], 0, 0, 0, 0x7F7F7F7F, 0, 0x79797979);
            acc[1][0] = __builtin_amdgcn_mfma_scale_f32_32x32x64_f8f6f4(
                af1, bf0, acc[1][0], 0, 0, 0, 0x7F7F7F7F, 0, 0x79797979);
            acc[1][1] = __builtin_amdgcn_mfma_scale_f32_32x32x64_f8f6f4(
                af1, bf1, acc[1][1], 0, 0, 0, 0x7F7F7F7F, 0, 0x79797979);
        }

        __syncthreads();  // protect buffer before next tile's DMA
    }

    // epilogue: 32x32 C/D: col = lane&31, row = (reg&3)+8*(reg>>2)+4*(lane>>5)
#pragma unroll
    for (int n = 0; n < 2; ++n) {
        int col = bcol0 + wc * 64 + n * 32 + rl;
        float bv = bias[col];
#pragma unroll
        for (int m = 0; m < 2; ++m) {
            int rowb = arow0 + wr * 64 + m * 32 + g2 * 4;
#pragma unroll
            for (int reg = 0; reg < 16; ++reg) {
                int row = rowb + (reg & 3) + 8 * (reg >> 2);
                C[(size_t)row * N + col] = acc[m][n][reg] + bv;
            }
        }
    }
}

extern "C" void kernel_launch(void* const* d_in, const int* in_sizes, int n_in,
                              void* d_out, int out_size, void* d_ws, size_t ws_size,
                              hipStream_t stream) {
    const float* x = (const float*)d_in[0];     // [M,K]
    const float* w = (const float*)d_in[1];     // [N,K]
    const float* bias = (const float*)d_in[2];  // [N]
    float* out = (float*)d_out;

    const int N = in_sizes[2];                 // 16384
    const int K = in_sizes[1] / N;             // 4096
    const int M = in_sizes[0] / K;             // 8192

    unsigned char* xq = (unsigned char*)d_ws;          // M*K = 33.5 MB
    unsigned char* wq = xq + (size_t)M * K;            // N*K = 67 MB

    int nx8 = M * K / 8;
    int nw8 = N * K / 8;
    quant8<<<(nx8 + 255) / 256, 256, 0, stream>>>(
        (const float4*)x, (int2*)xq, nx8, 1.0f);
    quant8<<<(nw8 + 255) / 256, 256, 0, stream>>>(
        (const float4*)w, (int2*)wq, nw8, 64.0f);

    int nwg = (M / BM) * (N / BN);  // 64*64 = 4096, %8==0
    gemm_fp8<<<nwg, 512, 0, stream>>>(
        xq, wq, bias, out, M, N, K);
}